// Round 10
// baseline (841.793 us; speedup 1.0000x reference)
//
#include <hip/hip_runtime.h>
#include <stdint.h>

#define BB   64
#define QQ   1000
#define CC   1203
#define NROW (QQ*CC)         // 1203000
#define NROW4 (NROW/4)       // 300750
#define KSEL 1000
#define TOPKN 100
#define NBINS 8192
#define CAPN 4096
#define SLICE 128            // cand slots per (row, chunk); 32 * 128 = 4096 = CAPN
#define GRIDX 32             // chunks per row
#define BLK   512
#define CHUNK ((NROW4 + GRIDX - 1) / GRIDX)   // 9399 float4 per block, contiguous
#define SPEC_VAL 3.0f        // row mean 1624 (15 sigma > 1000); chunk mean 51 (10.8 sigma < 128)

// native clang vector type for nontemporal builtins (HIP_vector_type is rejected)
typedef float nt4 __attribute__((ext_vector_type(4)));

// workspace byte offsets (only done[] needs zeroing: 256 B)
#define WS_DONE  0                                   // BB*4 = 256 B
#define WS_BCNT  256                                 // BB*GRIDX*4 = 8192 B
#define WS_CAND  (256 + BB*GRIDX*4)
#define WS_QSEL  (WS_CAND + (size_t)BB*CAPN*8)

// output float offsets (return-order concat)
#define O_SCORES 0
#define O_LABELS (BB*TOPKN)                      // 6400
#define O_BOXES  (2*BB*TOPKN)                    // 12800
#define O_PROB   (O_BOXES + BB*TOPKN*4)          // 38400
#define O_TIA    (O_PROB + (size_t)BB*TOPKN*CC)  // 7737600
#define O_BNORM  (O_TIA + BB*KSEL)               // 7801600

__device__ __forceinline__ uint32_t fkey(float f) {
    uint32_t x = __float_as_uint(f);
    return x ^ ((x & 0x80000000u) ? 0xFFFFFFFFu : 0x80000000u);
}
__device__ __forceinline__ float finv(uint32_t u) {
    uint32_t x = (u & 0x80000000u) ? (u ^ 0x80000000u) : ~u;
    return __uint_as_float(x);
}
__device__ __forceinline__ float sigmoidf_(float x) {
    if (x >= 0.0f) { float e = expf(-x); return 1.0f / (1.0f + e); }
    float e = expf(x); return e / (1.0f + e);
}

__device__ __forceinline__ void stash_elem(float val, uint32_t idx,
                                           uint32_t* lcnt, uint64_t* lbuf) {
    uint64_t pk = ((uint64_t)fkey(val) << 32) | (uint32_t)(~idx);
    uint32_t pos = atomicAdd(lcnt, 1u);
    if (pos < SLICE) lbuf[pos] = pk;
}
__device__ __forceinline__ void stash_vec(nt4 v, int i4,
                                          uint32_t* lcnt, uint64_t* lbuf) {
    float m = fmaxf(fmaxf(v.x, v.y), fmaxf(v.z, v.w));
    if (m >= SPEC_VAL) {                       // one branch per 4 elems; body is rare
        if (v.x >= SPEC_VAL) stash_elem(v.x, (uint32_t)(i4 * 4 + 0), lcnt, lbuf);
        if (v.y >= SPEC_VAL) stash_elem(v.y, (uint32_t)(i4 * 4 + 1), lcnt, lbuf);
        if (v.z >= SPEC_VAL) stash_elem(v.z, (uint32_t)(i4 * 4 + 2), lcnt, lbuf);
        if (v.w >= SPEC_VAL) stash_elem(v.w, (uint32_t)(i4 * 4 + 3), lcnt, lbuf);
    }
}

// ---- fused: stash chunk; last-finishing block of each row compacts+sorts+writes ----
__global__ void __launch_bounds__(BLK) k_fused(const nt4* __restrict__ lg4,
                                               uint32_t* __restrict__ done,
                                               uint32_t* __restrict__ bcnt,
                                               uint64_t* __restrict__ cand,
                                               const float4* __restrict__ pb4,
                                               const float* __restrict__ tsz,
                                               float* __restrict__ out,
                                               int* __restrict__ qsel) {
    __shared__ uint64_t s[CAPN];          // stash lbuf (first 128) / compact buf / fallback hist
    __shared__ uint32_t csum[BLK];
    __shared__ uint32_t scnt[GRIDX], soff[GRIDX + 1];
    __shared__ uint32_t lcnt, sh_n;
    __shared__ int sh_valid, sh_t, claim;
    const int b = blockIdx.y;
    const int blk = blockIdx.x;
    const int tid = threadIdx.x;
    uint64_t* lbuf = s;
    if (tid == 0) lcnt = 0;
    __syncthreads();
    const nt4* row = lg4 + (size_t)b * NROW4;
    const int start = blk * CHUNK;
    const int end = (start + CHUNK < NROW4) ? (start + CHUNK) : NROW4;

    int i = start + tid;
    // 8 independent nontemporal float4 loads in flight per thread
    for (; i + 7 * BLK < end; i += 8 * BLK) {
        nt4 v0 = __builtin_nontemporal_load(row + i);
        nt4 v1 = __builtin_nontemporal_load(row + i + BLK);
        nt4 v2 = __builtin_nontemporal_load(row + i + 2 * BLK);
        nt4 v3 = __builtin_nontemporal_load(row + i + 3 * BLK);
        nt4 v4 = __builtin_nontemporal_load(row + i + 4 * BLK);
        nt4 v5 = __builtin_nontemporal_load(row + i + 5 * BLK);
        nt4 v6 = __builtin_nontemporal_load(row + i + 6 * BLK);
        nt4 v7 = __builtin_nontemporal_load(row + i + 7 * BLK);
        stash_vec(v0, i,           &lcnt, lbuf);
        stash_vec(v1, i + BLK,     &lcnt, lbuf);
        stash_vec(v2, i + 2 * BLK, &lcnt, lbuf);
        stash_vec(v3, i + 3 * BLK, &lcnt, lbuf);
        stash_vec(v4, i + 4 * BLK, &lcnt, lbuf);
        stash_vec(v5, i + 5 * BLK, &lcnt, lbuf);
        stash_vec(v6, i + 6 * BLK, &lcnt, lbuf);
        stash_vec(v7, i + 7 * BLK, &lcnt, lbuf);
    }
    for (; i < end; i += BLK) {
        nt4 v = __builtin_nontemporal_load(row + i);
        stash_vec(v, i, &lcnt, lbuf);
    }
    __syncthreads();
    {
        const uint32_t c = lcnt;
        uint64_t* slice = cand + ((size_t)b * GRIDX + blk) * SLICE;
        uint32_t n0 = (c < SLICE) ? c : SLICE;
        for (uint32_t i2 = tid; i2 < n0; i2 += BLK) slice[i2] = lbuf[i2];
        if (tid == 0) bcnt[b * GRIDX + blk] = c;
    }
    __threadfence();                         // release: slice + bcnt visible device-wide
    __syncthreads();
    if (tid == 0) {
        uint32_t old = atomicAdd(&done[b], 1u);
        claim = (old == GRIDX - 1);          // last finisher owns the row
    }
    __syncthreads();
    if (!claim) return;
    __threadfence();                         // acquire: other blocks' slices/bcnt

    // ---- claimer: compact + sort + outputs (512 threads) ----
    uint32_t n;
    const uint64_t* pcand = cand + (size_t)b * CAPN;
    if (tid < 64) {                          // wave 0: scan 32 counts
        uint32_t c2 = (tid < GRIDX) ? bcnt[b * GRIDX + tid] : 0u;
        unsigned long long bad = __ballot(c2 > SLICE);
        uint32_t cc = (c2 < SLICE) ? c2 : SLICE;
        uint32_t inc = cc;
#pragma unroll
        for (int off = 1; off < GRIDX; off <<= 1) {
            uint32_t up = __shfl_up(inc, off, 64);
            if (tid >= off) inc += up;
        }
        if (tid < GRIDX) { scnt[tid] = cc; soff[tid] = inc - cc; }
        if (tid == GRIDX - 1) {
            soff[GRIDX] = inc;
            sh_valid = (bad == 0ull) && inc >= (uint32_t)KSEL;
        }
    }
    __syncthreads();

    if (sh_valid) {
        n = soff[GRIDX];
        for (int k = tid >> 6; k < GRIDX; k += 8) {       // 8 groups of 64 threads
            for (uint32_t idx = tid & 63; idx < scnt[k]; idx += 64)
                s[soff[k] + idx] = pcand[(size_t)k * SLICE + idx];
        }
    } else {
        // ---- fallback: exact per-row selection in-block (never taken for sane data) ----
        uint32_t* hs = (uint32_t*)s;
        for (int i2 = tid; i2 < NBINS; i2 += BLK) hs[i2] = 0;
        __syncthreads();
        for (int i2 = tid; i2 < NROW4; i2 += BLK) {
            nt4 v = row[i2];
            atomicAdd(&hs[fkey(v.x) >> 19], 1u);
            atomicAdd(&hs[fkey(v.y) >> 19], 1u);
            atomicAdd(&hs[fkey(v.z) >> 19], 1u);
            atomicAdd(&hs[fkey(v.w) >> 19], 1u);
        }
        __syncthreads();
        const int base = tid * 16;
        uint32_t ssum = 0;
#pragma unroll
        for (int k = 0; k < 16; ++k) ssum += hs[base + k];
        csum[tid] = ssum;
        __syncthreads();
        for (int off = 1; off < BLK; off <<= 1) {
            uint32_t v = csum[tid];
            uint32_t a = (tid + off < BLK) ? csum[tid + off] : 0u;
            __syncthreads();
            csum[tid] = v + a;
            __syncthreads();
        }
        if (csum[tid] >= KSEL && (tid == BLK - 1 || csum[tid + 1] < KSEL)) {
            uint32_t acc = (tid == BLK - 1) ? 0u : csum[tid + 1];
            int t = base;
            for (int k = 15; k >= 0; --k) {
                acc += hs[base + k];
                if (acc >= KSEL) { t = base + k; break; }
            }
            sh_t = t;
        }
        if (tid == 0) sh_n = 0;
        __syncthreads();
        const uint32_t ts = (uint32_t)sh_t;   // hist dead after this barrier
        for (int i2 = tid; i2 < NROW4; i2 += BLK) {
            nt4 v = row[i2];
            float c4[4] = {v.x, v.y, v.z, v.w};
#pragma unroll
            for (int j = 0; j < 4; ++j) {
                uint32_t u = fkey(c4[j]);
                if ((u >> 19) >= ts) {
                    uint32_t pos = atomicAdd(&sh_n, 1u);
                    if (pos < CAPN)
                        s[pos] = ((uint64_t)u << 32) | (uint32_t)(~(uint32_t)(i2 * 4 + j));
                }
            }
        }
        __syncthreads();
        n = sh_n;
    }
    if (n > CAPN) n = CAPN;
    const unsigned cap = (n <= 2048u) ? 2048u : 4096u;
    for (unsigned i2 = n + tid; i2 < cap; i2 += BLK) s[i2] = 0ull;
    __syncthreads();

    // bitonic sort, descending composite (key desc, idx asc on ties); cap/2 CEs per step
    for (unsigned k = 2; k <= cap; k <<= 1) {
        for (unsigned j = k >> 1; j > 0; j >>= 1) {
            for (unsigned w = tid; w < (cap >> 1); w += BLK) {
                unsigned i2 = ((w & ~(j - 1)) << 1) | (w & (j - 1));
                unsigned ixj = i2 | j;
                uint64_t a = s[i2], c = s[ixj];
                bool up = ((i2 & k) == 0);
                if (up ? (a < c) : (a > c)) { s[i2] = c; s[ixj] = a; }
            }
            __syncthreads();
        }
    }

    for (int jj = tid; jj < KSEL; jj += BLK) {
        uint64_t c = s[jj];
        uint32_t idx = ~((uint32_t)c);
        uint32_t q = idx / (uint32_t)CC;
        out[O_TIA + b * KSEL + jj] = (float)q;
    }
    if (tid < TOPKN) {
        uint64_t c = s[tid];
        uint32_t u = (uint32_t)(c >> 32);
        uint32_t idx = ~((uint32_t)c);
        uint32_t q = idx / (uint32_t)CC;
        uint32_t lab = idx - q * (uint32_t)CC;
        float logit = finv(u);
        out[O_SCORES + b * TOPKN + tid] = sigmoidf_(logit);
        out[O_LABELS + b * TOPKN + tid] = (float)lab;
        qsel[b * TOPKN + tid] = (int)q;
        float4 pb = pb4[b * QQ + q];
        float x0 = pb.x - 0.5f * pb.z;
        float y0 = pb.y - 0.5f * pb.w;
        float x1 = pb.x + 0.5f * pb.z;
        float y1 = pb.y + 0.5f * pb.w;
        float ih = tsz[b * 2 + 0];
        float iw = tsz[b * 2 + 1];
        float4* obn = (float4*)(out + O_BNORM);
        float4* obx = (float4*)(out + O_BOXES);
        obn[b * TOPKN + tid] = make_float4(x0, y0, x1, y1);
        obx[b * TOPKN + tid] = make_float4(x0 * iw, y0 * ih, x1 * iw, y1 * ih);
    }
}

// ---------------- pass 2: topk_inst_prob gather + sigmoid (batched, NT stores) --------
__global__ void __launch_bounds__(256) k_prob(const float* __restrict__ lg,
                                              const int* __restrict__ qsel,
                                              float* __restrict__ out) {
    const int r = blockIdx.x;          // 0..B*TOPK
    const int b = r / TOPKN;
    const int q = qsel[r];
    const int tid = threadIdx.x;
    const float* src = lg + ((size_t)b * QQ + q) * CC;
    float* dst = out + O_PROB + (size_t)r * CC;
    // CC = 1203 = 4*256 + 179: issue all 5 loads before any sigmoid
    float v0 = src[tid];
    float v1 = src[tid + 256];
    float v2 = src[tid + 512];
    float v3 = src[tid + 768];
    float v4 = (tid < CC - 1024) ? src[tid + 1024] : 0.0f;
    __builtin_nontemporal_store(sigmoidf_(v0), dst + tid);
    __builtin_nontemporal_store(sigmoidf_(v1), dst + tid + 256);
    __builtin_nontemporal_store(sigmoidf_(v2), dst + tid + 512);
    __builtin_nontemporal_store(sigmoidf_(v3), dst + tid + 768);
    if (tid < CC - 1024) __builtin_nontemporal_store(sigmoidf_(v4), dst + tid + 1024);
}

extern "C" void kernel_launch(void* const* d_in, const int* in_sizes, int n_in,
                              void* d_out, int out_size, void* d_ws, size_t ws_size,
                              hipStream_t stream) {
    const float* logits = (const float*)d_in[0];
    const float* boxes  = (const float*)d_in[1];
    const float* tsz    = (const float*)d_in[2];
    float* out = (float*)d_out;
    uint8_t* ws = (uint8_t*)d_ws;

    uint32_t* done = (uint32_t*)(ws + WS_DONE);
    uint32_t* bcnt = (uint32_t*)(ws + WS_BCNT);
    uint64_t* cand = (uint64_t*)(ws + WS_CAND);
    int*      qsel = (int*)(ws + WS_QSEL);

    (void)hipMemsetAsync(done, 0, BB * sizeof(uint32_t), stream);

    dim3 gs(GRIDX, BB);
    k_fused<<<gs, BLK, 0, stream>>>((const nt4*)logits, done, bcnt, cand,
                                    (const float4*)boxes, tsz, out, qsel);
    k_prob<<<BB * TOPKN, 256, 0, stream>>>(logits, qsel, out);
}

// Round 11
// 87.748 us; speedup vs baseline: 9.5933x; 9.5933x over previous
//
#include <hip/hip_runtime.h>
#include <stdint.h>

#define BB   64
#define QQ   1000
#define CC   1203
#define NROW (QQ*CC)         // 1203000
#define NROW4 (NROW/4)       // 300750
#define KSEL 1000
#define TOPKN 100
#define NBINS 8192
#define CAPN 4096
#define SLICE 64             // cand slots per (row, chunk); 64 * 64 = 4096 = CAPN
#define GRIDX 64             // == wavefront size: bcnt scan fits one wave
#define CHUNK ((NROW4 + GRIDX - 1) / GRIDX)   // 4700 float4 per block, contiguous
#define SPEC_VAL 3.0f        // row mean 1624 (15 sigma > 1000); chunk mean 25.4 (7.9 sigma < 64)

// native clang vector type for nontemporal builtins (HIP_vector_type is rejected)
typedef float nt4 __attribute__((ext_vector_type(4)));

// workspace byte offsets (no zeroing needed: every word read is overwritten first)
#define WS_BCNT  0                                   // BB*GRIDX*4 = 16384 B
#define WS_CAND  (BB*GRIDX*4)
#define WS_QSEL  (WS_CAND + (size_t)BB*CAPN*8)

// output float offsets (return-order concat)
#define O_SCORES 0
#define O_LABELS (BB*TOPKN)                      // 6400
#define O_BOXES  (2*BB*TOPKN)                    // 12800
#define O_PROB   (O_BOXES + BB*TOPKN*4)          // 38400
#define O_TIA    (O_PROB + (size_t)BB*TOPKN*CC)  // 7737600
#define O_BNORM  (O_TIA + BB*KSEL)               // 7801600

__device__ __forceinline__ uint32_t fkey(float f) {
    uint32_t x = __float_as_uint(f);
    return x ^ ((x & 0x80000000u) ? 0xFFFFFFFFu : 0x80000000u);
}
__device__ __forceinline__ float finv(uint32_t u) {
    uint32_t x = (u & 0x80000000u) ? (u ^ 0x80000000u) : ~u;
    return __uint_as_float(x);
}
__device__ __forceinline__ float sigmoidf_(float x) {
    if (x >= 0.0f) { float e = expf(-x); return 1.0f / (1.0f + e); }
    float e = expf(x); return e / (1.0f + e);
}

// ---------------- pass 1: single-pass speculative stash, contiguous chunk/block --------
__device__ __forceinline__ void stash_elem(float val, uint32_t idx,
                                           uint32_t* lcnt, uint64_t* lbuf) {
    uint64_t pk = ((uint64_t)fkey(val) << 32) | (uint32_t)(~idx);
    uint32_t pos = atomicAdd(lcnt, 1u);
    if (pos < SLICE) lbuf[pos] = pk;
}
__device__ __forceinline__ void stash_vec(nt4 v, int i4,
                                          uint32_t* lcnt, uint64_t* lbuf) {
    float m = fmaxf(fmaxf(v.x, v.y), fmaxf(v.z, v.w));
    if (m >= SPEC_VAL) {                       // one branch per 4 elems; body is rare
        if (v.x >= SPEC_VAL) stash_elem(v.x, (uint32_t)(i4 * 4 + 0), lcnt, lbuf);
        if (v.y >= SPEC_VAL) stash_elem(v.y, (uint32_t)(i4 * 4 + 1), lcnt, lbuf);
        if (v.z >= SPEC_VAL) stash_elem(v.z, (uint32_t)(i4 * 4 + 2), lcnt, lbuf);
        if (v.w >= SPEC_VAL) stash_elem(v.w, (uint32_t)(i4 * 4 + 3), lcnt, lbuf);
    }
}

__global__ void __launch_bounds__(256) k_stash(const nt4* __restrict__ lg4,
                                               uint32_t* __restrict__ bcnt,
                                               uint64_t* __restrict__ cand) {
    __shared__ uint64_t lbuf[SLICE];
    __shared__ uint32_t lcnt;
    const int b = blockIdx.y;
    const int blk = blockIdx.x;
    const int tid = threadIdx.x;
    if (tid == 0) lcnt = 0;
    __syncthreads();
    const nt4* row = lg4 + (size_t)b * NROW4;
    const int start = blk * CHUNK;
    const int end = (start + CHUNK < NROW4) ? (start + CHUNK) : NROW4;

    int i = start + tid;
    // 8 independent nontemporal float4 loads in flight per thread (zero reuse stream)
    for (; i + 1792 < end; i += 2048) {
        nt4 v0 = __builtin_nontemporal_load(row + i);
        nt4 v1 = __builtin_nontemporal_load(row + i + 256);
        nt4 v2 = __builtin_nontemporal_load(row + i + 512);
        nt4 v3 = __builtin_nontemporal_load(row + i + 768);
        nt4 v4 = __builtin_nontemporal_load(row + i + 1024);
        nt4 v5 = __builtin_nontemporal_load(row + i + 1280);
        nt4 v6 = __builtin_nontemporal_load(row + i + 1536);
        nt4 v7 = __builtin_nontemporal_load(row + i + 1792);
        stash_vec(v0, i,        &lcnt, lbuf);
        stash_vec(v1, i + 256,  &lcnt, lbuf);
        stash_vec(v2, i + 512,  &lcnt, lbuf);
        stash_vec(v3, i + 768,  &lcnt, lbuf);
        stash_vec(v4, i + 1024, &lcnt, lbuf);
        stash_vec(v5, i + 1280, &lcnt, lbuf);
        stash_vec(v6, i + 1536, &lcnt, lbuf);
        stash_vec(v7, i + 1792, &lcnt, lbuf);
    }
    for (; i < end; i += 256) {
        nt4 v = __builtin_nontemporal_load(row + i);
        stash_vec(v, i, &lcnt, lbuf);
    }
    __syncthreads();
    const uint32_t c = lcnt;
    uint64_t* slice = cand + ((size_t)b * GRIDX + blk) * SLICE;
    uint32_t n = (c < SLICE) ? c : SLICE;
    for (uint32_t i2 = tid; i2 < n; i2 += 256) slice[i2] = lbuf[i2];
    if (tid == 0) bcnt[b * GRIDX + blk] = c;   // overwrite (deterministic, no init needed)
}

// ---------------- pass 2: compact + sort + outputs; in-block exact fallback ----------------
__global__ void __launch_bounds__(1024) k_sortout(const float4* __restrict__ lg4,
                                                  const uint32_t* __restrict__ bcnt,
                                                  const uint64_t* __restrict__ cand,
                                                  const float4* __restrict__ pb4,
                                                  const float* __restrict__ tsz,
                                                  float* __restrict__ out,
                                                  int* __restrict__ qsel) {
    __shared__ uint64_t s[CAPN];          // 32 KiB; aliased as uint32 hist in fallback
    __shared__ uint32_t csum[1024];
    __shared__ uint32_t scnt[GRIDX], soff[GRIDX + 1];
    __shared__ int sh_valid;
    __shared__ uint32_t sh_n;
    __shared__ int sh_t;
    const int b = blockIdx.x;
    const int tid = threadIdx.x;
    const uint64_t* pcand = cand + (size_t)b * CAPN;
    uint32_t n;

    // wave-parallel bcnt scan: one coalesced 256B load + ballot + shfl_up prefix scan
    if (tid < GRIDX) {                      // GRIDX == 64 == one full wave
        uint32_t c = bcnt[b * GRIDX + tid];
        unsigned long long bad = __ballot(c > SLICE);
        uint32_t cc = (c < SLICE) ? c : SLICE;
        uint32_t inc = cc;
#pragma unroll
        for (int off = 1; off < 64; off <<= 1) {
            uint32_t up = __shfl_up(inc, off, 64);
            if (tid >= off) inc += up;
        }
        scnt[tid] = cc;
        soff[tid] = inc - cc;               // exclusive prefix
        if (tid == GRIDX - 1) {
            soff[GRIDX] = inc;              // total
            sh_valid = (bad == 0ull) && inc >= (uint32_t)KSEL;
        }
    }
    __syncthreads();

    if (sh_valid) {
        n = soff[GRIDX];
        // 16 slices per pass, 4 passes (tid>>6 in 0..15, idx = tid&63)
#pragma unroll
        for (int p = 0; p < 4; ++p) {
            int k = p * 16 + (tid >> 6);
            int idx = tid & 63;
            if ((uint32_t)idx < scnt[k]) s[soff[k] + idx] = pcand[k * SLICE + idx];
        }
    } else {
        // ---- fallback: exact per-row selection, fully in-block (never taken for sane data) ----
        uint32_t* hs = (uint32_t*)s;
        for (int i = tid; i < NBINS; i += 1024) hs[i] = 0;
        __syncthreads();
        const float4* row = lg4 + (size_t)b * NROW4;
        for (int i = tid; i < NROW4; i += 1024) {
            float4 v = row[i];
            atomicAdd(&hs[fkey(v.x) >> 19], 1u);
            atomicAdd(&hs[fkey(v.y) >> 19], 1u);
            atomicAdd(&hs[fkey(v.z) >> 19], 1u);
            atomicAdd(&hs[fkey(v.w) >> 19], 1u);
        }
        __syncthreads();
        const int base = tid * 8;
        uint32_t ssum = 0;
#pragma unroll
        for (int k = 0; k < 8; ++k) ssum += hs[base + k];
        csum[tid] = ssum;
        __syncthreads();
        for (int off = 1; off < 1024; off <<= 1) {
            uint32_t v = csum[tid];
            uint32_t a = (tid + off < 1024) ? csum[tid + off] : 0u;
            __syncthreads();
            csum[tid] = v + a;
            __syncthreads();
        }
        if (csum[tid] >= KSEL && (tid == 1023 || csum[tid + 1] < KSEL)) {
            uint32_t acc = (tid == 1023) ? 0u : csum[tid + 1];
            int t = base;
            for (int k = 7; k >= 0; --k) {
                acc += hs[base + k];
                if (acc >= KSEL) { t = base + k; break; }
            }
            sh_t = t;
        }
        if (tid == 0) sh_n = 0;
        __syncthreads();
        const uint32_t ts = (uint32_t)sh_t;   // after this barrier nobody reads hs again
        for (int i = tid; i < NROW4; i += 1024) {
            float4 v = row[i];
            float c4[4] = {v.x, v.y, v.z, v.w};
#pragma unroll
            for (int j = 0; j < 4; ++j) {
                uint32_t u = fkey(c4[j]);
                if ((u >> 19) >= ts) {
                    uint32_t pos = atomicAdd(&sh_n, 1u);
                    if (pos < CAPN)
                        s[pos] = ((uint64_t)u << 32) | (uint32_t)(~(uint32_t)(i * 4 + j));
                }
            }
        }
        __syncthreads();
        n = sh_n;
    }
    if (n > CAPN) n = CAPN;
    const unsigned cap = (n <= 2048u) ? 2048u : 4096u;
    for (unsigned i = n + tid; i < cap; i += 1024) s[i] = 0ull;
    __syncthreads();

    // bitonic sort, descending composite (key desc, idx asc on ties)
    // direct pair indexing: exactly cap/2 compare-exchanges per step, no idle pass
    for (unsigned k = 2; k <= cap; k <<= 1) {
        for (unsigned j = k >> 1; j > 0; j >>= 1) {
            for (unsigned w = tid; w < (cap >> 1); w += 1024) {
                unsigned i = ((w & ~(j - 1)) << 1) | (w & (j - 1));
                unsigned ixj = i | j;
                uint64_t a = s[i], c = s[ixj];
                bool up = ((i & k) == 0);
                if (up ? (a < c) : (a > c)) { s[i] = c; s[ixj] = a; }
            }
            __syncthreads();
        }
    }

    for (int jj = tid; jj < KSEL; jj += 1024) {
        uint64_t c = s[jj];
        uint32_t idx = ~((uint32_t)c);
        uint32_t q = idx / (uint32_t)CC;
        out[O_TIA + b * KSEL + jj] = (float)q;
    }
    if (tid < TOPKN) {
        uint64_t c = s[tid];
        uint32_t u = (uint32_t)(c >> 32);
        uint32_t idx = ~((uint32_t)c);
        uint32_t q = idx / (uint32_t)CC;
        uint32_t lab = idx - q * (uint32_t)CC;
        float logit = finv(u);
        out[O_SCORES + b * TOPKN + tid] = sigmoidf_(logit);
        out[O_LABELS + b * TOPKN + tid] = (float)lab;
        qsel[b * TOPKN + tid] = (int)q;
        float4 pb = pb4[b * QQ + q];
        float x0 = pb.x - 0.5f * pb.z;
        float y0 = pb.y - 0.5f * pb.w;
        float x1 = pb.x + 0.5f * pb.z;
        float y1 = pb.y + 0.5f * pb.w;
        float ih = tsz[b * 2 + 0];
        float iw = tsz[b * 2 + 1];
        float4* obn = (float4*)(out + O_BNORM);
        float4* obx = (float4*)(out + O_BOXES);
        obn[b * TOPKN + tid] = make_float4(x0, y0, x1, y1);
        obx[b * TOPKN + tid] = make_float4(x0 * iw, y0 * ih, x1 * iw, y1 * ih);
    }
}

// ---------------- pass 3: topk_inst_prob gather + sigmoid (batched loads, NT stores) ----
__global__ void __launch_bounds__(256) k_prob(const float* __restrict__ lg,
                                              const int* __restrict__ qsel,
                                              float* __restrict__ out) {
    const int r = blockIdx.x;          // 0..B*TOPK
    const int b = r / TOPKN;
    const int q = qsel[r];
    const int tid = threadIdx.x;
    const float* src = lg + ((size_t)b * QQ + q) * CC;
    float* dst = out + O_PROB + (size_t)r * CC;
    // CC = 1203 = 4*256 + 179: issue all 5 loads before any sigmoid
    float v0 = src[tid];
    float v1 = src[tid + 256];
    float v2 = src[tid + 512];
    float v3 = src[tid + 768];
    float v4 = (tid < CC - 1024) ? src[tid + 1024] : 0.0f;
    __builtin_nontemporal_store(sigmoidf_(v0), dst + tid);
    __builtin_nontemporal_store(sigmoidf_(v1), dst + tid + 256);
    __builtin_nontemporal_store(sigmoidf_(v2), dst + tid + 512);
    __builtin_nontemporal_store(sigmoidf_(v3), dst + tid + 768);
    if (tid < CC - 1024) __builtin_nontemporal_store(sigmoidf_(v4), dst + tid + 1024);
}

extern "C" void kernel_launch(void* const* d_in, const int* in_sizes, int n_in,
                              void* d_out, int out_size, void* d_ws, size_t ws_size,
                              hipStream_t stream) {
    const float* logits = (const float*)d_in[0];
    const float* boxes  = (const float*)d_in[1];
    const float* tsz    = (const float*)d_in[2];
    float* out = (float*)d_out;
    uint8_t* ws = (uint8_t*)d_ws;

    uint32_t* bcnt = (uint32_t*)(ws + WS_BCNT);
    uint64_t* cand = (uint64_t*)(ws + WS_CAND);
    int*      qsel = (int*)(ws + WS_QSEL);

    dim3 gs(GRIDX, BB);
    k_stash<<<gs, 256, 0, stream>>>((const nt4*)logits, bcnt, cand);
    k_sortout<<<BB, 1024, 0, stream>>>((const float4*)logits, bcnt, cand,
                                       (const float4*)boxes, tsz, out, qsel);
    k_prob<<<BB * TOPKN, 256, 0, stream>>>(logits, qsel, out);
}

// Round 12
// 86.787 us; speedup vs baseline: 9.6995x; 1.0111x over previous
//
#include <hip/hip_runtime.h>
#include <stdint.h>

#define BB   64
#define QQ   1000
#define CC   1203
#define NROW (QQ*CC)         // 1203000
#define NROW4 (NROW/4)       // 300750
#define KSEL 1000
#define TOPKN 100
#define NBINS 8192
#define CAPN 4096
#define SLICE 64             // cand slots per (row, chunk); 64 * 64 = 4096 = CAPN
#define GRIDX 64             // == wavefront size: bcnt scan fits one wave
#define CHUNK ((NROW4 + GRIDX - 1) / GRIDX)   // 4700 float4 per block, contiguous
#define SPEC_VAL 3.0f        // row mean 1624 (15 sigma > 1000); chunk mean 25.4 (7.9 sigma < 64)

// native clang vector type for nontemporal builtins (HIP_vector_type is rejected)
typedef float nt4 __attribute__((ext_vector_type(4)));

// workspace byte offsets (no zeroing needed: every word read is overwritten first)
#define WS_BCNT  0                                   // BB*GRIDX*4 = 16384 B
#define WS_CAND  (BB*GRIDX*4)
#define WS_QSEL  (WS_CAND + (size_t)BB*CAPN*8)

// output float offsets (return-order concat)
#define O_SCORES 0
#define O_LABELS (BB*TOPKN)                      // 6400
#define O_BOXES  (2*BB*TOPKN)                    // 12800
#define O_PROB   (O_BOXES + BB*TOPKN*4)          // 38400
#define O_TIA    (O_PROB + (size_t)BB*TOPKN*CC)  // 7737600
#define O_BNORM  (O_TIA + BB*KSEL)               // 7801600

__device__ __forceinline__ uint32_t fkey(float f) {
    uint32_t x = __float_as_uint(f);
    return x ^ ((x & 0x80000000u) ? 0xFFFFFFFFu : 0x80000000u);
}
__device__ __forceinline__ float finv(uint32_t u) {
    uint32_t x = (u & 0x80000000u) ? (u ^ 0x80000000u) : ~u;
    return __uint_as_float(x);
}
__device__ __forceinline__ float sigmoidf_(float x) {
    if (x >= 0.0f) { float e = expf(-x); return 1.0f / (1.0f + e); }
    float e = expf(x); return e / (1.0f + e);
}

// ---------------- pass 1: single-pass speculative stash, contiguous chunk/block --------
__device__ __forceinline__ void stash_elem(float val, uint32_t idx,
                                           uint32_t* lcnt, uint64_t* lbuf) {
    uint64_t pk = ((uint64_t)fkey(val) << 32) | (uint32_t)(~idx);
    uint32_t pos = atomicAdd(lcnt, 1u);
    if (pos < SLICE) lbuf[pos] = pk;
}
__device__ __forceinline__ void stash_vec(nt4 v, int i4,
                                          uint32_t* lcnt, uint64_t* lbuf) {
    float m = fmaxf(fmaxf(v.x, v.y), fmaxf(v.z, v.w));
    if (m >= SPEC_VAL) {                       // one branch per 4 elems; body is rare
        if (v.x >= SPEC_VAL) stash_elem(v.x, (uint32_t)(i4 * 4 + 0), lcnt, lbuf);
        if (v.y >= SPEC_VAL) stash_elem(v.y, (uint32_t)(i4 * 4 + 1), lcnt, lbuf);
        if (v.z >= SPEC_VAL) stash_elem(v.z, (uint32_t)(i4 * 4 + 2), lcnt, lbuf);
        if (v.w >= SPEC_VAL) stash_elem(v.w, (uint32_t)(i4 * 4 + 3), lcnt, lbuf);
    }
}

__global__ void __launch_bounds__(256) k_stash(const nt4* __restrict__ lg4,
                                               uint32_t* __restrict__ bcnt,
                                               uint64_t* __restrict__ cand) {
    __shared__ uint64_t lbuf[SLICE];
    __shared__ uint32_t lcnt;
    const int b = blockIdx.y;
    const int blk = blockIdx.x;
    const int tid = threadIdx.x;
    if (tid == 0) lcnt = 0;
    __syncthreads();
    const nt4* row = lg4 + (size_t)b * NROW4;
    const int start = blk * CHUNK;
    const int end = (start + CHUNK < NROW4) ? (start + CHUNK) : NROW4;
    const int last = end - 1;

    // whole chunk 8-deep: clamp upper load addresses (redundant loads are cache-hits),
    // guard the stash calls by the true bounds
    for (int i = start + tid; i < end; i += 2048) {
        const int i1 = (i + 256  <= last) ? i + 256  : last;
        const int i2 = (i + 512  <= last) ? i + 512  : last;
        const int i3 = (i + 768  <= last) ? i + 768  : last;
        const int i4 = (i + 1024 <= last) ? i + 1024 : last;
        const int i5 = (i + 1280 <= last) ? i + 1280 : last;
        const int i6 = (i + 1536 <= last) ? i + 1536 : last;
        const int i7 = (i + 1792 <= last) ? i + 1792 : last;
        nt4 v0 = __builtin_nontemporal_load(row + i);
        nt4 v1 = __builtin_nontemporal_load(row + i1);
        nt4 v2 = __builtin_nontemporal_load(row + i2);
        nt4 v3 = __builtin_nontemporal_load(row + i3);
        nt4 v4 = __builtin_nontemporal_load(row + i4);
        nt4 v5 = __builtin_nontemporal_load(row + i5);
        nt4 v6 = __builtin_nontemporal_load(row + i6);
        nt4 v7 = __builtin_nontemporal_load(row + i7);
        stash_vec(v0, i, &lcnt, lbuf);
        if (i + 256  < end) stash_vec(v1, i + 256,  &lcnt, lbuf);
        if (i + 512  < end) stash_vec(v2, i + 512,  &lcnt, lbuf);
        if (i + 768  < end) stash_vec(v3, i + 768,  &lcnt, lbuf);
        if (i + 1024 < end) stash_vec(v4, i + 1024, &lcnt, lbuf);
        if (i + 1280 < end) stash_vec(v5, i + 1280, &lcnt, lbuf);
        if (i + 1536 < end) stash_vec(v6, i + 1536, &lcnt, lbuf);
        if (i + 1792 < end) stash_vec(v7, i + 1792, &lcnt, lbuf);
    }
    __syncthreads();
    const uint32_t c = lcnt;
    uint64_t* slice = cand + ((size_t)b * GRIDX + blk) * SLICE;
    uint32_t n = (c < SLICE) ? c : SLICE;
    for (uint32_t i2 = tid; i2 < n; i2 += 256) slice[i2] = lbuf[i2];
    if (tid == 0) bcnt[b * GRIDX + blk] = c;   // overwrite (deterministic, no init needed)
}

// ---------------- pass 2: compact + sort + outputs; in-block exact fallback ----------------
__global__ void __launch_bounds__(1024) k_sortout(const float4* __restrict__ lg4,
                                                  const uint32_t* __restrict__ bcnt,
                                                  const uint64_t* __restrict__ cand,
                                                  const float4* __restrict__ pb4,
                                                  const float* __restrict__ tsz,
                                                  float* __restrict__ out,
                                                  int* __restrict__ qsel) {
    __shared__ uint64_t s[CAPN];          // 32 KiB; aliased as uint32 hist in fallback
    __shared__ uint32_t csum[1024];
    __shared__ uint32_t scnt[GRIDX], soff[GRIDX + 1];
    __shared__ int sh_valid;
    __shared__ uint32_t sh_n;
    __shared__ int sh_t;
    const int b = blockIdx.x;
    const int tid = threadIdx.x;
    const uint64_t* pcand = cand + (size_t)b * CAPN;
    uint32_t n;

    // wave-parallel bcnt scan: one coalesced 256B load + ballot + shfl_up prefix scan
    if (tid < GRIDX) {                      // GRIDX == 64 == one full wave
        uint32_t c = bcnt[b * GRIDX + tid];
        unsigned long long bad = __ballot(c > SLICE);
        uint32_t cc = (c < SLICE) ? c : SLICE;
        uint32_t inc = cc;
#pragma unroll
        for (int off = 1; off < 64; off <<= 1) {
            uint32_t up = __shfl_up(inc, off, 64);
            if (tid >= off) inc += up;
        }
        scnt[tid] = cc;
        soff[tid] = inc - cc;               // exclusive prefix
        if (tid == GRIDX - 1) {
            soff[GRIDX] = inc;              // total
            sh_valid = (bad == 0ull) && inc >= (uint32_t)KSEL;
        }
    }
    __syncthreads();

    if (sh_valid) {
        n = soff[GRIDX];
        // 16 slices per pass, 4 passes (tid>>6 in 0..15, idx = tid&63)
#pragma unroll
        for (int p = 0; p < 4; ++p) {
            int k = p * 16 + (tid >> 6);
            int idx = tid & 63;
            if ((uint32_t)idx < scnt[k]) s[soff[k] + idx] = pcand[k * SLICE + idx];
        }
    } else {
        // ---- fallback: exact per-row selection, fully in-block (never taken for sane data) ----
        uint32_t* hs = (uint32_t*)s;
        for (int i = tid; i < NBINS; i += 1024) hs[i] = 0;
        __syncthreads();
        const float4* row = lg4 + (size_t)b * NROW4;
        for (int i = tid; i < NROW4; i += 1024) {
            float4 v = row[i];
            atomicAdd(&hs[fkey(v.x) >> 19], 1u);
            atomicAdd(&hs[fkey(v.y) >> 19], 1u);
            atomicAdd(&hs[fkey(v.z) >> 19], 1u);
            atomicAdd(&hs[fkey(v.w) >> 19], 1u);
        }
        __syncthreads();
        const int base = tid * 8;
        uint32_t ssum = 0;
#pragma unroll
        for (int k = 0; k < 8; ++k) ssum += hs[base + k];
        csum[tid] = ssum;
        __syncthreads();
        for (int off = 1; off < 1024; off <<= 1) {
            uint32_t v = csum[tid];
            uint32_t a = (tid + off < 1024) ? csum[tid + off] : 0u;
            __syncthreads();
            csum[tid] = v + a;
            __syncthreads();
        }
        if (csum[tid] >= KSEL && (tid == 1023 || csum[tid + 1] < KSEL)) {
            uint32_t acc = (tid == 1023) ? 0u : csum[tid + 1];
            int t = base;
            for (int k = 7; k >= 0; --k) {
                acc += hs[base + k];
                if (acc >= KSEL) { t = base + k; break; }
            }
            sh_t = t;
        }
        if (tid == 0) sh_n = 0;
        __syncthreads();
        const uint32_t ts = (uint32_t)sh_t;   // after this barrier nobody reads hs again
        for (int i = tid; i < NROW4; i += 1024) {
            float4 v = row[i];
            float c4[4] = {v.x, v.y, v.z, v.w};
#pragma unroll
            for (int j = 0; j < 4; ++j) {
                uint32_t u = fkey(c4[j]);
                if ((u >> 19) >= ts) {
                    uint32_t pos = atomicAdd(&sh_n, 1u);
                    if (pos < CAPN)
                        s[pos] = ((uint64_t)u << 32) | (uint32_t)(~(uint32_t)(i * 4 + j));
                }
            }
        }
        __syncthreads();
        n = sh_n;
    }
    if (n > CAPN) n = CAPN;
    const unsigned cap = (n <= 2048u) ? 2048u : 4096u;
    for (unsigned i = n + tid; i < cap; i += 1024) s[i] = 0ull;
    __syncthreads();

    // bitonic sort, descending composite (key desc, idx asc on ties)
    // direct pair indexing: exactly cap/2 compare-exchanges per step, no idle pass
    for (unsigned k = 2; k <= cap; k <<= 1) {
        for (unsigned j = k >> 1; j > 0; j >>= 1) {
            for (unsigned w = tid; w < (cap >> 1); w += 1024) {
                unsigned i = ((w & ~(j - 1)) << 1) | (w & (j - 1));
                unsigned ixj = i | j;
                uint64_t a = s[i], c = s[ixj];
                bool up = ((i & k) == 0);
                if (up ? (a < c) : (a > c)) { s[i] = c; s[ixj] = a; }
            }
            __syncthreads();
        }
    }

    for (int jj = tid; jj < KSEL; jj += 1024) {
        uint64_t c = s[jj];
        uint32_t idx = ~((uint32_t)c);
        uint32_t q = idx / (uint32_t)CC;
        out[O_TIA + b * KSEL + jj] = (float)q;
    }
    if (tid < TOPKN) {
        uint64_t c = s[tid];
        uint32_t u = (uint32_t)(c >> 32);
        uint32_t idx = ~((uint32_t)c);
        uint32_t q = idx / (uint32_t)CC;
        uint32_t lab = idx - q * (uint32_t)CC;
        float logit = finv(u);
        out[O_SCORES + b * TOPKN + tid] = sigmoidf_(logit);
        out[O_LABELS + b * TOPKN + tid] = (float)lab;
        qsel[b * TOPKN + tid] = (int)q;
        float4 pb = pb4[b * QQ + q];
        float x0 = pb.x - 0.5f * pb.z;
        float y0 = pb.y - 0.5f * pb.w;
        float x1 = pb.x + 0.5f * pb.z;
        float y1 = pb.y + 0.5f * pb.w;
        float ih = tsz[b * 2 + 0];
        float iw = tsz[b * 2 + 1];
        float4* obn = (float4*)(out + O_BNORM);
        float4* obx = (float4*)(out + O_BOXES);
        obn[b * TOPKN + tid] = make_float4(x0, y0, x1, y1);
        obx[b * TOPKN + tid] = make_float4(x0 * iw, y0 * ih, x1 * iw, y1 * ih);
    }
}

// ---------------- pass 3: topk_inst_prob gather + sigmoid (batched loads, NT stores) ----
__global__ void __launch_bounds__(256) k_prob(const float* __restrict__ lg,
                                              const int* __restrict__ qsel,
                                              float* __restrict__ out) {
    const int r = blockIdx.x;          // 0..B*TOPK
    const int b = r / TOPKN;
    const int q = qsel[r];
    const int tid = threadIdx.x;
    const float* src = lg + ((size_t)b * QQ + q) * CC;
    float* dst = out + O_PROB + (size_t)r * CC;
    // CC = 1203 = 4*256 + 179: issue all 5 loads before any sigmoid
    float v0 = src[tid];
    float v1 = src[tid + 256];
    float v2 = src[tid + 512];
    float v3 = src[tid + 768];
    float v4 = (tid < CC - 1024) ? src[tid + 1024] : 0.0f;
    __builtin_nontemporal_store(sigmoidf_(v0), dst + tid);
    __builtin_nontemporal_store(sigmoidf_(v1), dst + tid + 256);
    __builtin_nontemporal_store(sigmoidf_(v2), dst + tid + 512);
    __builtin_nontemporal_store(sigmoidf_(v3), dst + tid + 768);
    if (tid < CC - 1024) __builtin_nontemporal_store(sigmoidf_(v4), dst + tid + 1024);
}

extern "C" void kernel_launch(void* const* d_in, const int* in_sizes, int n_in,
                              void* d_out, int out_size, void* d_ws, size_t ws_size,
                              hipStream_t stream) {
    const float* logits = (const float*)d_in[0];
    const float* boxes  = (const float*)d_in[1];
    const float* tsz    = (const float*)d_in[2];
    float* out = (float*)d_out;
    uint8_t* ws = (uint8_t*)d_ws;

    uint32_t* bcnt = (uint32_t*)(ws + WS_BCNT);
    uint64_t* cand = (uint64_t*)(ws + WS_CAND);
    int*      qsel = (int*)(ws + WS_QSEL);

    dim3 gs(GRIDX, BB);
    k_stash<<<gs, 256, 0, stream>>>((const nt4*)logits, bcnt, cand);
    k_sortout<<<BB, 1024, 0, stream>>>((const float4*)logits, bcnt, cand,
                                       (const float4*)boxes, tsz, out, qsel);
    k_prob<<<BB * TOPKN, 256, 0, stream>>>(logits, qsel, out);
}